// Round 5
// baseline (1073.263 us; speedup 1.0000x reference)
//
#include <hip/hip_runtime.h>

// Conformer block — bf16 MFMA everywhere; round 5: attention q-tile 128
// (512 thr, 8 waves), merged Sg/Ps LDS buffer, occupancy 29%->~75%.
// B=16 N=1024 DIM=512 H=8 DH=64 FF=2048 CIN=1024 K=31 MAXPOS=512. BN=16384.

#define BN 16384

typedef unsigned short u16;
typedef __attribute__((ext_vector_type(8))) __bf16 bf16x8;
typedef __attribute__((ext_vector_type(4))) float f32x4;
typedef __attribute__((ext_vector_type(8))) unsigned short u16x8;

__device__ __forceinline__ float sigf(float x) { return 1.f / (1.f + __expf(-x)); }
__device__ __forceinline__ u16 f2bf(float f) {
  unsigned int u = __float_as_uint(f);
  u += 0x7FFF + ((u >> 16) & 1);
  return (u16)(u >> 16);
}
__device__ __forceinline__ float bf2f(u16 u) {
  return __uint_as_float(((unsigned int)u) << 16);
}
__device__ __forceinline__ void gl_lds16(const void* g, void* lds) {
  __builtin_amdgcn_global_load_lds(
      (const __attribute__((address_space(1))) unsigned int*)g,
      (__attribute__((address_space(3))) unsigned int*)lds, 16, 0, 0);
}

// ---------------------------------------------------------------- layernorm
__global__ __launch_bounds__(256) void ln_kernel(const float* __restrict__ in,
    const float* __restrict__ g, const float* __restrict__ b,
    u16* outb, float* outf) {
  const int row = blockIdx.x;
  const int t = threadIdx.x;
  const float2 v = ((const float2*)(in + (size_t)row * 512))[t];
  float s = v.x + v.y;
  float sq = v.x * v.x + v.y * v.y;
#pragma unroll
  for (int o = 32; o > 0; o >>= 1) {
    s += __shfl_down(s, o);
    sq += __shfl_down(sq, o);
  }
  __shared__ float ss[4], ssq[4];
  if ((t & 63) == 0) { ss[t >> 6] = s; ssq[t >> 6] = sq; }
  __syncthreads();
  s = ss[0] + ss[1] + ss[2] + ss[3];
  sq = ssq[0] + ssq[1] + ssq[2] + ssq[3];
  const float mu = s * (1.f / 512.f);
  const float var = fmaxf(sq * (1.f / 512.f) - mu * mu, 0.f);
  const float rstd = rsqrtf(var + 1e-5f);
  const float2 gg = ((const float2*)g)[t];
  const float2 bb = ((const float2*)b)[t];
  float ox = (v.x - mu) * rstd * gg.x + bb.x;
  float oy = (v.y - mu) * rstd * gg.y + bb.y;
  if (outf) {
    float2 o2 = {ox, oy};
    ((float2*)(outf + (size_t)row * 512))[t] = o2;
  } else {
    ushort2 u2 = {f2bf(ox), f2bf(oy)};
    ((ushort2*)(outb + (size_t)row * 512))[t] = u2;
  }
}

// ---------------------------------------------------------------- weight prep
__global__ __launch_bounds__(256) void wtrans(const float* __restrict__ W,
                                              u16* __restrict__ WT, int K, int N) {
  const int n0 = blockIdx.x * 32, k0 = blockIdx.y * 32;
  const int t = threadIdx.x;
  const int tx = t & 31, ty = t >> 5;
  __shared__ float T[32][33];
#pragma unroll
  for (int i = 0; i < 4; ++i)
    T[tx][ty + 8 * i] = W[(size_t)(k0 + ty + 8 * i) * N + n0 + tx];
  __syncthreads();
#pragma unroll
  for (int i = 0; i < 4; ++i)
    WT[(size_t)(n0 + ty + 8 * i) * K + k0 + tx] = f2bf(T[ty + 8 * i][tx]);
}

__global__ __launch_bounds__(256) void cvt_bf16(const float* __restrict__ in,
                                                u16* __restrict__ out, int n) {
  const int i = blockIdx.x * 256 + threadIdx.x;
  if (i < n) out[i] = f2bf(in[i]);
}

// ---------------------------------------------------------------- bf16 MFMA gemm
__global__ __launch_bounds__(256) void gemm_bf16(const u16* __restrict__ A,
    const u16* __restrict__ WT, const float* __restrict__ bias,
    const float* res, float* Cf, u16* Cb, int K, int N, float alpha, int act) {
  __shared__ __align__(16) u16 Ast[128 * 32];
  __shared__ __align__(16) u16 Bst[128 * 32];
  const int t = threadIdx.x;
  const int n0 = blockIdx.x * 128;
  const int m0 = blockIdx.y * 128;
  const int w = t >> 6;
  const int lc = t & 15, lq = (t >> 4) & 3;
  const int wy = w >> 1, wx = w & 1;
  f32x4 acc[4][4];
#pragma unroll
  for (int i = 0; i < 4; ++i)
#pragma unroll
    for (int j = 0; j < 4; ++j)
#pragma unroll
      for (int r = 0; r < 4; ++r) acc[i][j][r] = 0.f;

  for (int kt = 0; kt < K; kt += 32) {
#pragma unroll
    for (int s = 0; s < 2; ++s) {
      const int f = t + 256 * s;
      gl_lds16(&A[(size_t)(m0 + (f >> 2)) * K + kt + (f & 3) * 8], &Ast[f * 8]);
      gl_lds16(&WT[(size_t)(n0 + (f >> 2)) * K + kt + (f & 3) * 8], &Bst[f * 8]);
    }
    __syncthreads();
    bf16x8 bfr[4];
#pragma unroll
    for (int j = 0; j < 4; ++j)
      bfr[j] = *(const bf16x8*)&Bst[(wx * 64 + j * 16 + lc) * 32 + lq * 8];
#pragma unroll
    for (int i = 0; i < 4; ++i) {
      const bf16x8 af = *(const bf16x8*)&Ast[(wy * 64 + i * 16 + lc) * 32 + lq * 8];
#pragma unroll
      for (int j = 0; j < 4; ++j)
        acc[i][j] = __builtin_amdgcn_mfma_f32_16x16x32_bf16(af, bfr[j], acc[i][j], 0, 0, 0);
    }
    __syncthreads();
  }

#pragma unroll
  for (int j = 0; j < 4; ++j) {
    const int col = n0 + wx * 64 + j * 16 + lc;
    const float bj = bias ? bias[col] : 0.f;
#pragma unroll
    for (int i = 0; i < 4; ++i) {
      const int row0 = m0 + wy * 64 + i * 16 + lq * 4;
#pragma unroll
      for (int r = 0; r < 4; ++r) {
        float v = acc[i][j][r] + bj;
        if (act) v = v * sigf(v);
        v *= alpha;
        const size_t off = (size_t)(row0 + r) * N + col;
        if (res) v += res[off];
        if (Cf) Cf[off] = v;
        else Cb[off] = f2bf(v);
      }
    }
  }
}

// ---------------------------------------------------------------- V transpose
// VT[(b*8+h)*64 + d][n] = QKV[b*1024+n][1024 + h*64 + d]   (QKV stride 1536)
__global__ __launch_bounds__(256) void vtrans(const u16* __restrict__ QKV,
                                              u16* __restrict__ VT) {
  const int n0 = blockIdx.x * 64;
  const int h = blockIdx.y, b = blockIdx.z;
  const int t = threadIdx.x;
  __shared__ u16 T[64][65];
#pragma unroll
  for (int s = 0; s < 2; ++s) {
    const int f = t + 256 * s;
    const int n = f >> 3, off = (f & 7) * 8;
    u16x8 v = *(const u16x8*)&QKV[(size_t)(b * 1024 + n0 + n) * 1536 + 1024 + h * 64 + off];
#pragma unroll
    for (int e = 0; e < 8; ++e) T[n][off + e] = v[e];
  }
  __syncthreads();
#pragma unroll
  for (int s = 0; s < 2; ++s) {
    const int f = t + 256 * s;
    const int d = f >> 3, off = (f & 7) * 8;
    u16x8 v;
#pragma unroll
    for (int e = 0; e < 8; ++e) v[e] = T[off + e][d];
    *(u16x8*)&VT[(size_t)((b * 8 + h) * 64 + d) * 1024 + n0 + off] = v;
  }
}

// ---------------------------------------------------------------- flash attention (MFMA)
// Round 5: q-tile = 128 rows, 512 threads = 8 waves (wave w owns q rows
// [w*16, w*16+16)); one 64-wide K/V tile serves all 128 q rows (staging =
// 1 chunk/thread/jt). SP buffer merged: skew-scattered pos values are read
// and overwritten in place by exp(S) (same thread, same address). Streaming
// softmax (scores analytically bounded), deferred denominator reduce.
// XCD swizzle: all 8 q-tiles of one (b,h) on one XCD (lin&127 = hb).
__global__ __launch_bounds__(512) void attn_mfma(const u16* __restrict__ QKV,
    const u16* __restrict__ Vt, const u16* __restrict__ Rb, u16* __restrict__ O) {
  const int lin = blockIdx.x;
  const int hb = lin & 127;            // (b,h) group
  const int n0 = (lin >> 7) * 128;     // q-tile (128 rows)
  const int h = hb & 7, b = hb >> 3;
  const int t = threadIdx.x;           // 0..511
  const int w = t >> 6;                // wave 0..7
  const int lc = t & 15, lq = (t >> 4) & 3;

  __shared__ __align__(16) u16 Ks[64 * 72];
  __shared__ __align__(16) u16 Vs[64 * 72];    // Vs[d][j]
  __shared__ __align__(16) u16 SP[128 * 72];   // pos scatter, then exp(S) in place

  // Q fragments in registers: A[m=lc][k = ks*32 + lq*8 ..+8]
  bf16x8 qf[2];
  {
    const size_t qrow = (size_t)(b * 1024 + n0 + w * 16 + lc) * 1536 + h * 64;
    qf[0] = *(const bf16x8*)&QKV[qrow + lq * 8];
    qf[1] = *(const bf16x8*)&QKV[qrow + 32 + lq * 8];
  }

  float l_r[4] = {0.f, 0.f, 0.f, 0.f};
  f32x4 o[4];
#pragma unroll
  for (int dt = 0; dt < 4; ++dt)
#pragma unroll
    for (int r = 0; r < 4; ++r) o[dt][r] = 0.f;

  const float SC = 0.125f * 1.44269504f;  // scale * log2(e)

  for (int jt = 0; jt < 16; ++jt) {
    const int j0 = jt * 64;
    // staging: 512 threads, exactly one 16B chunk each for K and for V
    {
      const int row = t >> 3, c8 = (t & 7) * 8;
      const u16x8 kv =
          *(const u16x8*)&QKV[(size_t)(b * 1024 + j0 + row) * 1536 + 512 + h * 64 + c8];
      const u16x8 vv =
          *(const u16x8*)&Vt[(size_t)((b * 8 + h) * 64 + row) * 1024 + j0 + c8];
      *(u16x8*)&Ks[row * 72 + c8] = kv;
      *(u16x8*)&Vs[row * 72 + c8] = vv;
    }
    __syncthreads();

    f32x4 qk[4], pa[5];
#pragma unroll
    for (int j = 0; j < 4; ++j)
#pragma unroll
      for (int r = 0; r < 4; ++r) qk[j][r] = 0.f;
#pragma unroll
    for (int rtl = 0; rtl < 5; ++rtl)
#pragma unroll
      for (int r = 0; r < 4; ++r) pa[rtl][r] = 0.f;

    const int base = n0 - j0 - 63;
#pragma unroll
    for (int ks = 0; ks < 2; ++ks) {
      bf16x8 rfr[5];
#pragma unroll
      for (int rtl = 0; rtl < 5; ++rtl) {
        const int didx = (w + rtl) * 16 + lc;
        int p = base + didx;
        p = (p < -512 ? -512 : (p > 512 ? 512 : p)) + 512;
        rfr[rtl] = *(const bf16x8*)&Rb[(size_t)p * 64 + ks * 32 + lq * 8];
      }
#pragma unroll
      for (int j = 0; j < 4; ++j) {
        const bf16x8 bf = *(const bf16x8*)&Ks[(j * 16 + lc) * 72 + ks * 32 + lq * 8];
        qk[j] = __builtin_amdgcn_mfma_f32_16x16x32_bf16(qf[ks], bf, qk[j], 0, 0, 0);
      }
#pragma unroll
      for (int rtl = 0; rtl < 5; ++rtl)
        pa[rtl] = __builtin_amdgcn_mfma_f32_16x16x32_bf16(qf[ks], rfr[rtl], pa[rtl], 0, 0, 0);
    }

    // skewed scatter: P[qr][didx] -> SP[qr][jc], jc = qr - didx + 63 (wave-local rows)
#pragma unroll
    for (int rtl = 0; rtl < 5; ++rtl) {
      const int didx = (w + rtl) * 16 + lc;
#pragma unroll
      for (int r = 0; r < 4; ++r) {
        const int qr = w * 16 + lq * 4 + r;
        const int jc = qr - didx + 63;
        if ((unsigned)jc < 64u) SP[qr * 72 + jc] = f2bf(pa[rtl][r]);
      }
    }

    // streaming softmax in place: read pos, write exp at the same slot
#pragma unroll
    for (int r = 0; r < 4; ++r) {
      const int qr = w * 16 + lq * 4 + r;
#pragma unroll
      for (int ti = 0; ti < 4; ++ti) {
        const int a = qr * 72 + ti * 16 + lc;
        const float sv = (qk[ti][r] + bf2f(SP[a])) * SC;
        const float e = exp2f(sv);
        SP[a] = f2bf(e);
        l_r[r] += e;
      }
    }

    // PV (SP rows wave-local; DS in-order within wave)
#pragma unroll
    for (int ks = 0; ks < 2; ++ks) {
      const bf16x8 af = *(const bf16x8*)&SP[(w * 16 + lc) * 72 + ks * 32 + lq * 8];
#pragma unroll
      for (int dt = 0; dt < 4; ++dt) {
        const bf16x8 bf = *(const bf16x8*)&Vs[(dt * 16 + lc) * 72 + ks * 32 + lq * 8];
        o[dt] = __builtin_amdgcn_mfma_f32_16x16x32_bf16(af, bf, o[dt], 0, 0, 0);
      }
    }
    __syncthreads();
  }

  // final denominator reduce across the 16-lane row group
#pragma unroll
  for (int r = 0; r < 4; ++r) {
#pragma unroll
    for (int msk = 1; msk < 16; msk <<= 1) l_r[r] += __shfl_xor(l_r[r], msk);
  }

#pragma unroll
  for (int r = 0; r < 4; ++r) {
    const float inv = 1.f / l_r[r];
    const size_t row = (size_t)(b * 1024 + n0 + w * 16 + lq * 4 + r);
#pragma unroll
    for (int dt = 0; dt < 4; ++dt)
      O[row * 512 + h * 64 + dt * 16 + lc] = f2bf(o[dt][r] * inv);
  }
}

// ---------------------------------------------------------------- GLU (bf16)
__global__ __launch_bounds__(256) void glu_kernel(const u16* __restrict__ in,
                                                  u16* __restrict__ out) {
  const size_t m = blockIdx.x;
  const int c4 = threadIdx.x * 4;
  const ushort4 a4 = *(const ushort4*)&in[m * 2048 + c4];
  const ushort4 g4 = *(const ushort4*)&in[m * 2048 + 1024 + c4];
  ushort4 o4;
  o4.x = f2bf(bf2f(a4.x) * sigf(bf2f(g4.x)));
  o4.y = f2bf(bf2f(a4.y) * sigf(bf2f(g4.y)));
  o4.z = f2bf(bf2f(a4.z) * sigf(bf2f(g4.z)));
  o4.w = f2bf(bf2f(a4.w) * sigf(bf2f(g4.w)));
  *(ushort4*)&out[m * 1024 + c4] = o4;
}

// ---------------------------------------------------------------- depthwise conv
__global__ __launch_bounds__(256) void dwconv_kernel(const u16* __restrict__ in,
    const float* __restrict__ w, const float* __restrict__ bias,
    u16* __restrict__ out) {
  const int n0 = blockIdx.x * 64;
  const int c0 = blockIdx.y * 64;
  const int b = blockIdx.z;
  const int t = threadIdx.x;
  __shared__ float hs[94][64];
  __shared__ float wsh[31][64];
  const int c = t & 63;
  const int g = t >> 6;
  for (int r = g; r < 94; r += 4) {
    const int n = n0 - 30 + r;
    hs[r][c] = (n >= 0) ? bf2f(in[(size_t)(b * 1024 + n) * 1024 + c0 + c]) : 0.f;
  }
  for (int idx = t; idx < 31 * 64; idx += 256) {
    const int tap = idx >> 6, cc = idx & 63;
    wsh[tap][cc] = w[(size_t)(c0 + cc) * 31 + tap];
  }
  __syncthreads();
  float wr[31];
#pragma unroll
  for (int k = 0; k < 31; ++k) wr[k] = wsh[k][c];
  const float bsv = bias[c0 + c];
  float win[46];
  const int rbase = g * 16;
#pragma unroll
  for (int k = 0; k < 46; ++k) win[k] = hs[rbase + k][c];
#pragma unroll
  for (int i = 0; i < 16; ++i) {
    float acc = bsv;
#pragma unroll
    for (int k = 0; k < 31; ++k) acc += wr[k] * win[i + k];
    acc = acc * sigf(acc);
    out[(size_t)(b * 1024 + n0 + rbase + i) * 1024 + c0 + c] = f2bf(acc);
  }
}

// ---------------------------------------------------------------- launch
extern "C" void kernel_launch(void* const* d_in, const int* in_sizes, int n_in,
                              void* d_out, int out_size, void* d_ws, size_t ws_size,
                              hipStream_t stream) {
  const float* x        = (const float*)d_in[0];
  const float* ff1_ln_g = (const float*)d_in[1];
  const float* ff1_ln_b = (const float*)d_in[2];
  const float* ff1_w1   = (const float*)d_in[3];
  const float* ff1_b1   = (const float*)d_in[4];
  const float* ff1_w2   = (const float*)d_in[5];
  const float* ff1_b2   = (const float*)d_in[6];
  const float* attn_ln_g= (const float*)d_in[7];
  const float* attn_ln_b= (const float*)d_in[8];
  const float* wq       = (const float*)d_in[9];
  const float* wkv      = (const float*)d_in[10];
  const float* wo       = (const float*)d_in[11];
  const float* bo       = (const float*)d_in[12];
  const float* rel_emb  = (const float*)d_in[13];
  const float* conv_ln_g= (const float*)d_in[14];
  const float* conv_ln_b= (const float*)d_in[15];
  const float* conv1_w  = (const float*)d_in[16];
  const float* conv1_b  = (const float*)d_in[17];
  const float* dw_w     = (const float*)d_in[18];
  const float* dw_b     = (const float*)d_in[19];
  const float* conv2_w  = (const float*)d_in[20];
  const float* conv2_b  = (const float*)d_in[21];
  const float* ff2_ln_g = (const float*)d_in[22];
  const float* ff2_ln_b = (const float*)d_in[23];
  const float* ff2_w1   = (const float*)d_in[24];
  const float* ff2_b1   = (const float*)d_in[25];
  const float* ff2_w2   = (const float*)d_in[26];
  const float* ff2_b2   = (const float*)d_in[27];
  const float* post_ln_g= (const float*)d_in[28];
  const float* post_ln_b= (const float*)d_in[29];

  float* XRES = (float*)d_out;
  u16* ws = (u16*)d_ws;
  u16* LNB  = ws;                                // BN*512
  u16* HID  = LNB + (size_t)BN * 512;            // BN*2048
  u16* QKVB = HID + (size_t)BN * 2048;           // BN*1536
  u16* VT   = QKVB + (size_t)BN * 1536;          // 8192*1024
  u16* GLUB = QKVB;                              // alias (QKV dead after attn)
  u16* DWB  = HID;                               // alias (HID dead after glu)
  u16* WTp = VT + (size_t)8192 * 1024;
  u16* wt_ff1w1 = WTp;                 WTp += (size_t)2048 * 512;
  u16* wt_ff1w2 = WTp;                 WTp += (size_t)512 * 2048;
  u16* wt_qkv   = WTp;                 WTp += (size_t)1536 * 512;
  u16* wt_wo    = WTp;                 WTp += (size_t)512 * 512;
  u16* wt_conv1 = WTp;                 WTp += (size_t)2048 * 512;
  u16* wt_conv2 = WTp;                 WTp += (size_t)512 * 1024;
  u16* wt_ff2w1 = WTp;                 WTp += (size_t)2048 * 512;
  u16* wt_ff2w2 = WTp;                 WTp += (size_t)512 * 2048;
  u16* RELB     = WTp;

  const dim3 blk(256);

  // weight prep
  wtrans<<<dim3(64, 16), blk, 0, stream>>>(ff1_w1, wt_ff1w1, 512, 2048);
  wtrans<<<dim3(16, 64), blk, 0, stream>>>(ff1_w2, wt_ff1w2, 2048, 512);
  wtrans<<<dim3(16, 16), blk, 0, stream>>>(wq, wt_qkv, 512, 512);
  wtrans<<<dim3(32, 16), blk, 0, stream>>>(wkv, wt_qkv + (size_t)512 * 512, 512, 1024);
  wtrans<<<dim3(16, 16), blk, 0, stream>>>(wo, wt_wo, 512, 512);
  wtrans<<<dim3(64, 16), blk, 0, stream>>>(conv1_w, wt_conv1, 512, 2048);
  wtrans<<<dim3(16, 32), blk, 0, stream>>>(conv2_w, wt_conv2, 1024, 512);
  wtrans<<<dim3(64, 16), blk, 0, stream>>>(ff2_w1, wt_ff2w1, 512, 2048);
  wtrans<<<dim3(16, 64), blk, 0, stream>>>(ff2_w2, wt_ff2w2, 2048, 512);
  cvt_bf16<<<257, blk, 0, stream>>>(rel_emb, RELB, 1025 * 64);

  // --- FF1 (half-step)
  ln_kernel<<<BN, blk, 0, stream>>>(x, ff1_ln_g, ff1_ln_b, LNB, nullptr);
  gemm_bf16<<<dim3(16, 128), blk, 0, stream>>>(LNB, wt_ff1w1, ff1_b1, nullptr,
                                               nullptr, HID, 512, 2048, 1.f, 1);
  gemm_bf16<<<dim3(4, 128), blk, 0, stream>>>(HID, wt_ff1w2, ff1_b2, x,
                                              XRES, nullptr, 2048, 512, 0.5f, 0);

  // --- attention
  ln_kernel<<<BN, blk, 0, stream>>>(XRES, attn_ln_g, attn_ln_b, LNB, nullptr);
  gemm_bf16<<<dim3(12, 128), blk, 0, stream>>>(LNB, wt_qkv, nullptr, nullptr,
                                               nullptr, QKVB, 512, 1536, 1.f, 0);
  vtrans<<<dim3(16, 8, 16), blk, 0, stream>>>(QKVB, VT);
  attn_mfma<<<dim3(1024), dim3(512), 0, stream>>>(QKVB, VT, RELB, LNB);
  gemm_bf16<<<dim3(4, 128), blk, 0, stream>>>(LNB, wt_wo, bo, XRES,
                                              XRES, nullptr, 512, 512, 1.f, 0);

  // --- conv module
  ln_kernel<<<BN, blk, 0, stream>>>(XRES, conv_ln_g, conv_ln_b, LNB, nullptr);
  gemm_bf16<<<dim3(16, 128), blk, 0, stream>>>(LNB, wt_conv1, conv1_b, nullptr,
                                               nullptr, HID, 512, 2048, 1.f, 0);
  glu_kernel<<<BN, blk, 0, stream>>>(HID, GLUB);
  dwconv_kernel<<<dim3(16, 16, 16), blk, 0, stream>>>(GLUB, dw_w, dw_b, DWB);
  gemm_bf16<<<dim3(4, 128), blk, 0, stream>>>(DWB, wt_conv2, conv2_b, XRES,
                                              XRES, nullptr, 1024, 512, 1.f, 0);

  // --- FF2 (half-step)
  ln_kernel<<<BN, blk, 0, stream>>>(XRES, ff2_ln_g, ff2_ln_b, LNB, nullptr);
  gemm_bf16<<<dim3(16, 128), blk, 0, stream>>>(LNB, wt_ff2w1, ff2_b1, nullptr,
                                               nullptr, HID, 512, 2048, 1.f, 1);
  gemm_bf16<<<dim3(4, 128), blk, 0, stream>>>(HID, wt_ff2w2, ff2_b2, XRES,
                                              XRES, nullptr, 2048, 512, 0.5f, 0);

  // --- final layernorm
  ln_kernel<<<BN, blk, 0, stream>>>(XRES, post_ln_g, post_ln_b, nullptr, XRES);
}

// Round 6
// 1023.524 us; speedup vs baseline: 1.0486x; 1.0486x over previous
//
#include <hip/hip_runtime.h>

// Conformer block — bf16 MFMA everywhere; round 6: r4 attn structure (4-wave
// q64 blocks) + merged in-place SP buffer (validated r5) + Q pre-scaled by
// 0.125*log2e at projection time (softmax loses the mul).
// B=16 N=1024 DIM=512 H=8 DH=64 FF=2048 CIN=1024 K=31 MAXPOS=512. BN=16384.

#define BN 16384

typedef unsigned short u16;
typedef __attribute__((ext_vector_type(8))) __bf16 bf16x8;
typedef __attribute__((ext_vector_type(4))) float f32x4;
typedef __attribute__((ext_vector_type(8))) unsigned short u16x8;

__device__ __forceinline__ float sigf(float x) { return 1.f / (1.f + __expf(-x)); }
__device__ __forceinline__ u16 f2bf(float f) {
  unsigned int u = __float_as_uint(f);
  u += 0x7FFF + ((u >> 16) & 1);
  return (u16)(u >> 16);
}
__device__ __forceinline__ float bf2f(u16 u) {
  return __uint_as_float(((unsigned int)u) << 16);
}
__device__ __forceinline__ void gl_lds16(const void* g, void* lds) {
  __builtin_amdgcn_global_load_lds(
      (const __attribute__((address_space(1))) unsigned int*)g,
      (__attribute__((address_space(3))) unsigned int*)lds, 16, 0, 0);
}

// ---------------------------------------------------------------- layernorm
__global__ __launch_bounds__(256) void ln_kernel(const float* __restrict__ in,
    const float* __restrict__ g, const float* __restrict__ b,
    u16* outb, float* outf) {
  const int row = blockIdx.x;
  const int t = threadIdx.x;
  const float2 v = ((const float2*)(in + (size_t)row * 512))[t];
  float s = v.x + v.y;
  float sq = v.x * v.x + v.y * v.y;
#pragma unroll
  for (int o = 32; o > 0; o >>= 1) {
    s += __shfl_down(s, o);
    sq += __shfl_down(sq, o);
  }
  __shared__ float ss[4], ssq[4];
  if ((t & 63) == 0) { ss[t >> 6] = s; ssq[t >> 6] = sq; }
  __syncthreads();
  s = ss[0] + ss[1] + ss[2] + ss[3];
  sq = ssq[0] + ssq[1] + ssq[2] + ssq[3];
  const float mu = s * (1.f / 512.f);
  const float var = fmaxf(sq * (1.f / 512.f) - mu * mu, 0.f);
  const float rstd = rsqrtf(var + 1e-5f);
  const float2 gg = ((const float2*)g)[t];
  const float2 bb = ((const float2*)b)[t];
  float ox = (v.x - mu) * rstd * gg.x + bb.x;
  float oy = (v.y - mu) * rstd * gg.y + bb.y;
  if (outf) {
    float2 o2 = {ox, oy};
    ((float2*)(outf + (size_t)row * 512))[t] = o2;
  } else {
    ushort2 u2 = {f2bf(ox), f2bf(oy)};
    ((ushort2*)(outb + (size_t)row * 512))[t] = u2;
  }
}

// ---------------------------------------------------------------- weight prep
__global__ __launch_bounds__(256) void wtrans(const float* __restrict__ W,
                                              u16* __restrict__ WT, int K, int N) {
  const int n0 = blockIdx.x * 32, k0 = blockIdx.y * 32;
  const int t = threadIdx.x;
  const int tx = t & 31, ty = t >> 5;
  __shared__ float T[32][33];
#pragma unroll
  for (int i = 0; i < 4; ++i)
    T[tx][ty + 8 * i] = W[(size_t)(k0 + ty + 8 * i) * N + n0 + tx];
  __syncthreads();
#pragma unroll
  for (int i = 0; i < 4; ++i)
    WT[(size_t)(n0 + ty + 8 * i) * K + k0 + tx] = f2bf(T[ty + 8 * i][tx]);
}

__global__ __launch_bounds__(256) void cvt_bf16(const float* __restrict__ in,
                                                u16* __restrict__ out, int n) {
  const int i = blockIdx.x * 256 + threadIdx.x;
  if (i < n) out[i] = f2bf(in[i]);
}

// ---------------------------------------------------------------- bf16 MFMA gemm
// C[M x N] = epi(A[M x K] @ WT[N x K]^T); C row stride = ldc (sub-block writes).
__global__ __launch_bounds__(256) void gemm_bf16(const u16* __restrict__ A,
    const u16* __restrict__ WT, const float* __restrict__ bias,
    const float* res, float* Cf, u16* Cb, int K, int N, int ldc,
    float alpha, int act) {
  __shared__ __align__(16) u16 Ast[128 * 32];
  __shared__ __align__(16) u16 Bst[128 * 32];
  const int t = threadIdx.x;
  const int n0 = blockIdx.x * 128;
  const int m0 = blockIdx.y * 128;
  const int w = t >> 6;
  const int lc = t & 15, lq = (t >> 4) & 3;
  const int wy = w >> 1, wx = w & 1;
  f32x4 acc[4][4];
#pragma unroll
  for (int i = 0; i < 4; ++i)
#pragma unroll
    for (int j = 0; j < 4; ++j)
#pragma unroll
      for (int r = 0; r < 4; ++r) acc[i][j][r] = 0.f;

  for (int kt = 0; kt < K; kt += 32) {
#pragma unroll
    for (int s = 0; s < 2; ++s) {
      const int f = t + 256 * s;
      gl_lds16(&A[(size_t)(m0 + (f >> 2)) * K + kt + (f & 3) * 8], &Ast[f * 8]);
      gl_lds16(&WT[(size_t)(n0 + (f >> 2)) * K + kt + (f & 3) * 8], &Bst[f * 8]);
    }
    __syncthreads();
    bf16x8 bfr[4];
#pragma unroll
    for (int j = 0; j < 4; ++j)
      bfr[j] = *(const bf16x8*)&Bst[(wx * 64 + j * 16 + lc) * 32 + lq * 8];
#pragma unroll
    for (int i = 0; i < 4; ++i) {
      const bf16x8 af = *(const bf16x8*)&Ast[(wy * 64 + i * 16 + lc) * 32 + lq * 8];
#pragma unroll
      for (int j = 0; j < 4; ++j)
        acc[i][j] = __builtin_amdgcn_mfma_f32_16x16x32_bf16(af, bfr[j], acc[i][j], 0, 0, 0);
    }
    __syncthreads();
  }

#pragma unroll
  for (int j = 0; j < 4; ++j) {
    const int col = n0 + wx * 64 + j * 16 + lc;
    const float bj = bias ? bias[col] : 0.f;
#pragma unroll
    for (int i = 0; i < 4; ++i) {
      const int row0 = m0 + wy * 64 + i * 16 + lq * 4;
#pragma unroll
      for (int r = 0; r < 4; ++r) {
        float v = acc[i][j][r] + bj;
        if (act) v = v * sigf(v);
        v *= alpha;
        const size_t off = (size_t)(row0 + r) * ldc + col;
        if (res) v += res[off];
        if (Cf) Cf[off] = v;
        else Cb[off] = f2bf(v);
      }
    }
  }
}

// ---------------------------------------------------------------- V transpose
// VT[(b*8+h)*64 + d][n] = QKV[b*1024+n][1024 + h*64 + d]   (QKV stride 1536)
__global__ __launch_bounds__(256) void vtrans(const u16* __restrict__ QKV,
                                              u16* __restrict__ VT) {
  const int n0 = blockIdx.x * 64;
  const int h = blockIdx.y, b = blockIdx.z;
  const int t = threadIdx.x;
  __shared__ u16 T[64][65];
#pragma unroll
  for (int s = 0; s < 2; ++s) {
    const int f = t + 256 * s;
    const int n = f >> 3, off = (f & 7) * 8;
    u16x8 v = *(const u16x8*)&QKV[(size_t)(b * 1024 + n0 + n) * 1536 + 1024 + h * 64 + off];
#pragma unroll
    for (int e = 0; e < 8; ++e) T[n][off + e] = v[e];
  }
  __syncthreads();
#pragma unroll
  for (int s = 0; s < 2; ++s) {
    const int f = t + 256 * s;
    const int d = f >> 3, off = (f & 7) * 8;
    u16x8 v;
#pragma unroll
    for (int e = 0; e < 8; ++e) v[e] = T[off + e][d];
    *(u16x8*)&VT[(size_t)((b * 8 + h) * 64 + d) * 1024 + n0 + off] = v;
  }
}

// ---------------------------------------------------------------- flash attention (MFMA)
// Round 6 = round 4 structure (q64, 4 waves) + merged in-place SP buffer +
// Q pre-scaled at projection (exp2 input is qk+pos directly, no mul).
// Streaming softmax (scores analytically bounded), deferred denom reduce.
// XCD swizzle: all 16 q-tiles of one (b,h) on one XCD (lin&127 = hb).
__global__ __launch_bounds__(256) void attn_mfma(const u16* __restrict__ QKV,
    const u16* __restrict__ Vt, const u16* __restrict__ Rb, u16* __restrict__ O) {
  const int lin = blockIdx.x;
  const int hb = lin & 127;            // (b,h) group
  const int n0 = (lin >> 7) * 64;      // q-tile
  const int h = hb & 7, b = hb >> 3;
  const int t = threadIdx.x;
  const int w = t >> 6;
  const int lc = t & 15, lq = (t >> 4) & 3;

  __shared__ __align__(16) u16 Ks[64 * 72];
  __shared__ __align__(16) u16 Vs[64 * 72];   // Vs[d][j]
  __shared__ __align__(16) u16 SP[64 * 72];   // pos scatter, then exp(S) in place

  // Q fragments in registers (Q already scaled by 0.125*log2e)
  bf16x8 qf[2];
  {
    const size_t qrow = (size_t)(b * 1024 + n0 + w * 16 + lc) * 1536 + h * 64;
    qf[0] = *(const bf16x8*)&QKV[qrow + lq * 8];
    qf[1] = *(const bf16x8*)&QKV[qrow + 32 + lq * 8];
  }

  float l_r[4] = {0.f, 0.f, 0.f, 0.f};
  f32x4 o[4];
#pragma unroll
  for (int dt = 0; dt < 4; ++dt)
#pragma unroll
    for (int r = 0; r < 4; ++r) o[dt][r] = 0.f;

  for (int jt = 0; jt < 16; ++jt) {
    const int j0 = jt * 64;
#pragma unroll
    for (int s = 0; s < 2; ++s) {
      const int f = t + 256 * s;
      const int row = f >> 3, c8 = (f & 7) * 8;
      const u16x8 kv =
          *(const u16x8*)&QKV[(size_t)(b * 1024 + j0 + row) * 1536 + 512 + h * 64 + c8];
      const u16x8 vv =
          *(const u16x8*)&Vt[(size_t)((b * 8 + h) * 64 + row) * 1024 + j0 + c8];
      *(u16x8*)&Ks[row * 72 + c8] = kv;
      *(u16x8*)&Vs[row * 72 + c8] = vv;
    }
    __syncthreads();

    f32x4 qk[4], pa[5];
#pragma unroll
    for (int j = 0; j < 4; ++j)
#pragma unroll
      for (int r = 0; r < 4; ++r) qk[j][r] = 0.f;
#pragma unroll
    for (int rtl = 0; rtl < 5; ++rtl)
#pragma unroll
      for (int r = 0; r < 4; ++r) pa[rtl][r] = 0.f;

    const int base = n0 - j0 - 63;
#pragma unroll
    for (int ks = 0; ks < 2; ++ks) {
      bf16x8 rfr[5];
#pragma unroll
      for (int rtl = 0; rtl < 5; ++rtl) {
        const int didx = (w + rtl) * 16 + lc;
        int p = base + didx;
        p = (p < -512 ? -512 : (p > 512 ? 512 : p)) + 512;
        rfr[rtl] = *(const bf16x8*)&Rb[(size_t)p * 64 + ks * 32 + lq * 8];
      }
#pragma unroll
      for (int j = 0; j < 4; ++j) {
        const bf16x8 bf = *(const bf16x8*)&Ks[(j * 16 + lc) * 72 + ks * 32 + lq * 8];
        qk[j] = __builtin_amdgcn_mfma_f32_16x16x32_bf16(qf[ks], bf, qk[j], 0, 0, 0);
      }
#pragma unroll
      for (int rtl = 0; rtl < 5; ++rtl)
        pa[rtl] = __builtin_amdgcn_mfma_f32_16x16x32_bf16(qf[ks], rfr[rtl], pa[rtl], 0, 0, 0);
    }

    // skewed scatter: P[qr][didx] -> SP[qr][jc], jc = qr - didx + 63 (wave-local)
#pragma unroll
    for (int rtl = 0; rtl < 5; ++rtl) {
      const int didx = (w + rtl) * 16 + lc;
#pragma unroll
      for (int r = 0; r < 4; ++r) {
        const int qr = w * 16 + lq * 4 + r;
        const int jc = qr - didx + 63;
        if ((unsigned)jc < 64u) SP[qr * 72 + jc] = f2bf(pa[rtl][r]);
      }
    }

    // streaming softmax in place (Q pre-scaled: exp2 of qk+pos directly)
#pragma unroll
    for (int r = 0; r < 4; ++r) {
      const int qr = w * 16 + lq * 4 + r;
#pragma unroll
      for (int ti = 0; ti < 4; ++ti) {
        const int a = qr * 72 + ti * 16 + lc;
        const float e = exp2f(qk[ti][r] + bf2f(SP[a]));
        SP[a] = f2bf(e);
        l_r[r] += e;
      }
    }

    // PV (SP rows wave-local; in-wave DS ordering suffices)
#pragma unroll
    for (int ks = 0; ks < 2; ++ks) {
      const bf16x8 af = *(const bf16x8*)&SP[(w * 16 + lc) * 72 + ks * 32 + lq * 8];
#pragma unroll
      for (int dt = 0; dt < 4; ++dt) {
        const bf16x8 bf = *(const bf16x8*)&Vs[(dt * 16 + lc) * 72 + ks * 32 + lq * 8];
        o[dt] = __builtin_amdgcn_mfma_f32_16x16x32_bf16(af, bf, o[dt], 0, 0, 0);
      }
    }
    __syncthreads();
  }

  // final denominator reduce across the 16-lane row group
#pragma unroll
  for (int r = 0; r < 4; ++r) {
#pragma unroll
    for (int msk = 1; msk < 16; msk <<= 1) l_r[r] += __shfl_xor(l_r[r], msk);
  }

#pragma unroll
  for (int r = 0; r < 4; ++r) {
    const float inv = 1.f / l_r[r];
    const size_t row = (size_t)(b * 1024 + n0 + w * 16 + lq * 4 + r);
#pragma unroll
    for (int dt = 0; dt < 4; ++dt)
      O[row * 512 + h * 64 + dt * 16 + lc] = f2bf(o[dt][r] * inv);
  }
}

// ---------------------------------------------------------------- GLU (bf16)
__global__ __launch_bounds__(256) void glu_kernel(const u16* __restrict__ in,
                                                  u16* __restrict__ out) {
  const size_t m = blockIdx.x;
  const int c4 = threadIdx.x * 4;
  const ushort4 a4 = *(const ushort4*)&in[m * 2048 + c4];
  const ushort4 g4 = *(const ushort4*)&in[m * 2048 + 1024 + c4];
  ushort4 o4;
  o4.x = f2bf(bf2f(a4.x) * sigf(bf2f(g4.x)));
  o4.y = f2bf(bf2f(a4.y) * sigf(bf2f(g4.y)));
  o4.z = f2bf(bf2f(a4.z) * sigf(bf2f(g4.z)));
  o4.w = f2bf(bf2f(a4.w) * sigf(bf2f(g4.w)));
  *(ushort4*)&out[m * 1024 + c4] = o4;
}

// ---------------------------------------------------------------- depthwise conv
__global__ __launch_bounds__(256) void dwconv_kernel(const u16* __restrict__ in,
    const float* __restrict__ w, const float* __restrict__ bias,
    u16* __restrict__ out) {
  const int n0 = blockIdx.x * 64;
  const int c0 = blockIdx.y * 64;
  const int b = blockIdx.z;
  const int t = threadIdx.x;
  __shared__ float hs[94][64];
  __shared__ float wsh[31][64];
  const int c = t & 63;
  const int g = t >> 6;
  for (int r = g; r < 94; r += 4) {
    const int n = n0 - 30 + r;
    hs[r][c] = (n >= 0) ? bf2f(in[(size_t)(b * 1024 + n) * 1024 + c0 + c]) : 0.f;
  }
  for (int idx = t; idx < 31 * 64; idx += 256) {
    const int tap = idx >> 6, cc = idx & 63;
    wsh[tap][cc] = w[(size_t)(c0 + cc) * 31 + tap];
  }
  __syncthreads();
  float wr[31];
#pragma unroll
  for (int k = 0; k < 31; ++k) wr[k] = wsh[k][c];
  const float bsv = bias[c0 + c];
  float win[46];
  const int rbase = g * 16;
#pragma unroll
  for (int k = 0; k < 46; ++k) win[k] = hs[rbase + k][c];
#pragma unroll
  for (int i = 0; i < 16; ++i) {
    float acc = bsv;
#pragma unroll
    for (int k = 0; k < 31; ++k) acc += wr[k] * win[i + k];
    acc = acc * sigf(acc);
    out[(size_t)(b * 1024 + n0 + rbase + i) * 1024 + c0 + c] = f2bf(acc);
  }
}

// ---------------------------------------------------------------- launch
extern "C" void kernel_launch(void* const* d_in, const int* in_sizes, int n_in,
                              void* d_out, int out_size, void* d_ws, size_t ws_size,
                              hipStream_t stream) {
  const float* x        = (const float*)d_in[0];
  const float* ff1_ln_g = (const float*)d_in[1];
  const float* ff1_ln_b = (const float*)d_in[2];
  const float* ff1_w1   = (const float*)d_in[3];
  const float* ff1_b1   = (const float*)d_in[4];
  const float* ff1_w2   = (const float*)d_in[5];
  const float* ff1_b2   = (const float*)d_in[6];
  const float* attn_ln_g= (const float*)d_in[7];
  const float* attn_ln_b= (const float*)d_in[8];
  const float* wq       = (const float*)d_in[9];
  const float* wkv      = (const float*)d_in[10];
  const float* wo       = (const float*)d_in[11];
  const float* bo       = (const float*)d_in[12];
  const float* rel_emb  = (const float*)d_in[13];
  const float* conv_ln_g= (const float*)d_in[14];
  const float* conv_ln_b= (const float*)d_in[15];
  const float* conv1_w  = (const float*)d_in[16];
  const float* conv1_b  = (const float*)d_in[17];
  const float* dw_w     = (const float*)d_in[18];
  const float* dw_b     = (const float*)d_in[19];
  const float* conv2_w  = (const float*)d_in[20];
  const float* conv2_b  = (const float*)d_in[21];
  const float* ff2_ln_g = (const float*)d_in[22];
  const float* ff2_ln_b = (const float*)d_in[23];
  const float* ff2_w1   = (const float*)d_in[24];
  const float* ff2_b1   = (const float*)d_in[25];
  const float* ff2_w2   = (const float*)d_in[26];
  const float* ff2_b2   = (const float*)d_in[27];
  const float* post_ln_g= (const float*)d_in[28];
  const float* post_ln_b= (const float*)d_in[29];

  float* XRES = (float*)d_out;
  u16* ws = (u16*)d_ws;
  u16* LNB  = ws;                                // BN*512
  u16* HID  = LNB + (size_t)BN * 512;            // BN*2048
  u16* QKVB = HID + (size_t)BN * 2048;           // BN*1536
  u16* VT   = QKVB + (size_t)BN * 1536;          // 8192*1024
  u16* GLUB = QKVB;                              // alias (QKV dead after attn)
  u16* DWB  = HID;                               // alias (HID dead after glu)
  u16* WTp = VT + (size_t)8192 * 1024;
  u16* wt_ff1w1 = WTp;                 WTp += (size_t)2048 * 512;
  u16* wt_ff1w2 = WTp;                 WTp += (size_t)512 * 2048;
  u16* wt_qkv   = WTp;                 WTp += (size_t)1536 * 512;
  u16* wt_wo    = WTp;                 WTp += (size_t)512 * 512;
  u16* wt_conv1 = WTp;                 WTp += (size_t)2048 * 512;
  u16* wt_conv2 = WTp;                 WTp += (size_t)512 * 1024;
  u16* wt_ff2w1 = WTp;                 WTp += (size_t)2048 * 512;
  u16* wt_ff2w2 = WTp;                 WTp += (size_t)512 * 2048;
  u16* RELB     = WTp;

  const dim3 blk(256);
  const float SC = 0.125f * 1.44269504f;  // folded into Q projection

  // weight prep
  wtrans<<<dim3(64, 16), blk, 0, stream>>>(ff1_w1, wt_ff1w1, 512, 2048);
  wtrans<<<dim3(16, 64), blk, 0, stream>>>(ff1_w2, wt_ff1w2, 2048, 512);
  wtrans<<<dim3(16, 16), blk, 0, stream>>>(wq, wt_qkv, 512, 512);
  wtrans<<<dim3(32, 16), blk, 0, stream>>>(wkv, wt_qkv + (size_t)512 * 512, 512, 1024);
  wtrans<<<dim3(16, 16), blk, 0, stream>>>(wo, wt_wo, 512, 512);
  wtrans<<<dim3(64, 16), blk, 0, stream>>>(conv1_w, wt_conv1, 512, 2048);
  wtrans<<<dim3(16, 32), blk, 0, stream>>>(conv2_w, wt_conv2, 1024, 512);
  wtrans<<<dim3(64, 16), blk, 0, stream>>>(ff2_w1, wt_ff2w1, 512, 2048);
  wtrans<<<dim3(16, 64), blk, 0, stream>>>(ff2_w2, wt_ff2w2, 2048, 512);
  cvt_bf16<<<257, blk, 0, stream>>>(rel_emb, RELB, 1025 * 64);

  // --- FF1 (half-step)
  ln_kernel<<<BN, blk, 0, stream>>>(x, ff1_ln_g, ff1_ln_b, LNB, nullptr);
  gemm_bf16<<<dim3(16, 128), blk, 0, stream>>>(LNB, wt_ff1w1, ff1_b1, nullptr,
                                               nullptr, HID, 512, 2048, 2048, 1.f, 1);
  gemm_bf16<<<dim3(4, 128), blk, 0, stream>>>(HID, wt_ff1w2, ff1_b2, x,
                                              XRES, nullptr, 2048, 512, 512, 0.5f, 0);

  // --- attention (Q projected with alpha=SC; K/V with alpha=1)
  ln_kernel<<<BN, blk, 0, stream>>>(XRES, attn_ln_g, attn_ln_b, LNB, nullptr);
  gemm_bf16<<<dim3(4, 128), blk, 0, stream>>>(LNB, wt_qkv, nullptr, nullptr,
                                              nullptr, QKVB, 512, 512, 1536, SC, 0);
  gemm_bf16<<<dim3(8, 128), blk, 0, stream>>>(LNB, wt_qkv + (size_t)512 * 512,
                                              nullptr, nullptr, nullptr, QKVB + 512,
                                              512, 1024, 1536, 1.f, 0);
  vtrans<<<dim3(16, 8, 16), blk, 0, stream>>>(QKVB, VT);
  attn_mfma<<<dim3(2048), blk, 0, stream>>>(QKVB, VT, RELB, LNB);
  gemm_bf16<<<dim3(4, 128), blk, 0, stream>>>(LNB, wt_wo, bo, XRES,
                                              XRES, nullptr, 512, 512, 512, 1.f, 0);

  // --- conv module
  ln_kernel<<<BN, blk, 0, stream>>>(XRES, conv_ln_g, conv_ln_b, LNB, nullptr);
  gemm_bf16<<<dim3(16, 128), blk, 0, stream>>>(LNB, wt_conv1, conv1_b, nullptr,
                                               nullptr, HID, 512, 2048, 2048, 1.f, 0);
  glu_kernel<<<BN, blk, 0, stream>>>(HID, GLUB);
  dwconv_kernel<<<dim3(16, 16, 16), blk, 0, stream>>>(GLUB, dw_w, dw_b, DWB);
  gemm_bf16<<<dim3(4, 128), blk, 0, stream>>>(DWB, wt_conv2, conv2_b, XRES,
                                              XRES, nullptr, 1024, 512, 512, 1.f, 0);

  // --- FF2 (half-step)
  ln_kernel<<<BN, blk, 0, stream>>>(XRES, ff2_ln_g, ff2_ln_b, LNB, nullptr);
  gemm_bf16<<<dim3(16, 128), blk, 0, stream>>>(LNB, wt_ff2w1, ff2_b1, nullptr,
                                               nullptr, HID, 512, 2048, 2048, 1.f, 1);
  gemm_bf16<<<dim3(4, 128), blk, 0, stream>>>(HID, wt_ff2w2, ff2_b2, XRES,
                                              XRES, nullptr, 2048, 512, 512, 0.5f, 0);

  // --- final layernorm
  ln_kernel<<<BN, blk, 0, stream>>>(XRES, post_ln_g, post_ln_b, nullptr, XRES);
}

// Round 7
// 963.819 us; speedup vs baseline: 1.1136x; 1.0619x over previous
//
#include <hip/hip_runtime.h>

// Conformer block — bf16 MFMA everywhere; round 7: GEMM XCD-locality swizzle
// (each XCD owns a contiguous band of m-tiles, column-fast => weights and
// active A-tiles stay L2-resident), vtrans fused into KV GEMM epilogue.
// B=16 N=1024 DIM=512 H=8 DH=64 FF=2048 CIN=1024 K=31 MAXPOS=512. BN=16384.

#define BN 16384

typedef unsigned short u16;
typedef __attribute__((ext_vector_type(8))) __bf16 bf16x8;
typedef __attribute__((ext_vector_type(4))) float f32x4;
typedef __attribute__((ext_vector_type(8))) unsigned short u16x8;

__device__ __forceinline__ float sigf(float x) { return 1.f / (1.f + __expf(-x)); }
__device__ __forceinline__ u16 f2bf(float f) {
  unsigned int u = __float_as_uint(f);
  u += 0x7FFF + ((u >> 16) & 1);
  return (u16)(u >> 16);
}
__device__ __forceinline__ float bf2f(u16 u) {
  return __uint_as_float(((unsigned int)u) << 16);
}
__device__ __forceinline__ void gl_lds16(const void* g, void* lds) {
  __builtin_amdgcn_global_load_lds(
      (const __attribute__((address_space(1))) unsigned int*)g,
      (__attribute__((address_space(3))) unsigned int*)lds, 16, 0, 0);
}

// ---------------------------------------------------------------- layernorm
__global__ __launch_bounds__(256) void ln_kernel(const float* __restrict__ in,
    const float* __restrict__ g, const float* __restrict__ b,
    u16* outb, float* outf) {
  const int row = blockIdx.x;
  const int t = threadIdx.x;
  const float2 v = ((const float2*)(in + (size_t)row * 512))[t];
  float s = v.x + v.y;
  float sq = v.x * v.x + v.y * v.y;
#pragma unroll
  for (int o = 32; o > 0; o >>= 1) {
    s += __shfl_down(s, o);
    sq += __shfl_down(sq, o);
  }
  __shared__ float ss[4], ssq[4];
  if ((t & 63) == 0) { ss[t >> 6] = s; ssq[t >> 6] = sq; }
  __syncthreads();
  s = ss[0] + ss[1] + ss[2] + ss[3];
  sq = ssq[0] + ssq[1] + ssq[2] + ssq[3];
  const float mu = s * (1.f / 512.f);
  const float var = fmaxf(sq * (1.f / 512.f) - mu * mu, 0.f);
  const float rstd = rsqrtf(var + 1e-5f);
  const float2 gg = ((const float2*)g)[t];
  const float2 bb = ((const float2*)b)[t];
  float ox = (v.x - mu) * rstd * gg.x + bb.x;
  float oy = (v.y - mu) * rstd * gg.y + bb.y;
  if (outf) {
    float2 o2 = {ox, oy};
    ((float2*)(outf + (size_t)row * 512))[t] = o2;
  } else {
    ushort2 u2 = {f2bf(ox), f2bf(oy)};
    ((ushort2*)(outb + (size_t)row * 512))[t] = u2;
  }
}

// ---------------------------------------------------------------- weight prep
__global__ __launch_bounds__(256) void wtrans(const float* __restrict__ W,
                                              u16* __restrict__ WT, int K, int N) {
  const int n0 = blockIdx.x * 32, k0 = blockIdx.y * 32;
  const int t = threadIdx.x;
  const int tx = t & 31, ty = t >> 5;
  __shared__ float T[32][33];
#pragma unroll
  for (int i = 0; i < 4; ++i)
    T[tx][ty + 8 * i] = W[(size_t)(k0 + ty + 8 * i) * N + n0 + tx];
  __syncthreads();
#pragma unroll
  for (int i = 0; i < 4; ++i)
    WT[(size_t)(n0 + ty + 8 * i) * K + k0 + tx] = f2bf(T[ty + 8 * i][tx]);
}

__global__ __launch_bounds__(256) void cvt_bf16(const float* __restrict__ in,
                                                u16* __restrict__ out, int n) {
  const int i = blockIdx.x * 256 + threadIdx.x;
  if (i < n) out[i] = f2bf(in[i]);
}

// ---------------------------------------------------------------- bf16 MFMA gemm
// C[M x N] = epi(A[M x K] @ WT[N x K]^T); C row stride = ldc.
// XCD swizzle: lin = bx + nx*by dispatches round-robin to XCDs (lin&7);
// remap so XCD k owns m-tiles [k*ny/8, (k+1)*ny/8), column-fast => weight
// matrix (<=2MB) and the active A m-tile stay resident in that XCD's L2.
// VTout: if set, cols >= 512 are V-head columns written TRANSPOSED into
// VT[(b*8+h)*64+d][n] as ushort4 (4 consecutive n per lane). Used by the
// KV projection to fuse the old vtrans kernel.
__global__ __launch_bounds__(256) void gemm_bf16(const u16* __restrict__ A,
    const u16* __restrict__ WT, const float* __restrict__ bias,
    const float* res, float* Cf, u16* Cb, u16* VTout, int K, int N, int ldc,
    float alpha, int act) {
  __shared__ __align__(16) u16 Ast[128 * 32];
  __shared__ __align__(16) u16 Bst[128 * 32];
  const int t = threadIdx.x;
  int bx = blockIdx.x, by = blockIdx.y;
  {
    const int nx = gridDim.x;
    const int lin = bx + nx * by;
    const int xcd = lin & 7;
    const int s = lin >> 3;
    const int ny8 = gridDim.y >> 3;
    const int sy = s / nx;
    by = xcd * ny8 + sy;
    bx = s - sy * nx;
  }
  const int n0 = bx * 128;
  const int m0 = by * 128;
  const int w = t >> 6;
  const int lc = t & 15, lq = (t >> 4) & 3;
  const int wy = w >> 1, wx = w & 1;
  f32x4 acc[4][4];
#pragma unroll
  for (int i = 0; i < 4; ++i)
#pragma unroll
    for (int j = 0; j < 4; ++j)
#pragma unroll
      for (int r = 0; r < 4; ++r) acc[i][j][r] = 0.f;

  for (int kt = 0; kt < K; kt += 32) {
#pragma unroll
    for (int s = 0; s < 2; ++s) {
      const int f = t + 256 * s;
      gl_lds16(&A[(size_t)(m0 + (f >> 2)) * K + kt + (f & 3) * 8], &Ast[f * 8]);
      gl_lds16(&WT[(size_t)(n0 + (f >> 2)) * K + kt + (f & 3) * 8], &Bst[f * 8]);
    }
    __syncthreads();
    bf16x8 bfr[4];
#pragma unroll
    for (int j = 0; j < 4; ++j)
      bfr[j] = *(const bf16x8*)&Bst[(wx * 64 + j * 16 + lc) * 32 + lq * 8];
#pragma unroll
    for (int i = 0; i < 4; ++i) {
      const bf16x8 af = *(const bf16x8*)&Ast[(wy * 64 + i * 16 + lc) * 32 + lq * 8];
#pragma unroll
      for (int j = 0; j < 4; ++j)
        acc[i][j] = __builtin_amdgcn_mfma_f32_16x16x32_bf16(af, bfr[j], acc[i][j], 0, 0, 0);
    }
    __syncthreads();
  }

#pragma unroll
  for (int j = 0; j < 4; ++j) {
    const int col = n0 + wx * 64 + j * 16 + lc;
    const float bj = bias ? bias[col] : 0.f;
    const bool vtc = (VTout != nullptr) && (col >= 512);
#pragma unroll
    for (int i = 0; i < 4; ++i) {
      const int row0 = m0 + wy * 64 + i * 16 + lq * 4;
      float v4[4];
#pragma unroll
      for (int r = 0; r < 4; ++r) {
        float v = acc[i][j][r] + bj;
        if (act) v = v * sigf(v);
        v *= alpha;
        if (res) v += res[(size_t)(row0 + r) * ldc + col];
        v4[r] = v;
      }
      if (vtc) {
        const int cm = col - 512;
        const int hh = cm >> 6, dd = cm & 63;
        const int bb = row0 >> 10, nl = row0 & 1023;
        ushort4 o4 = {f2bf(v4[0]), f2bf(v4[1]), f2bf(v4[2]), f2bf(v4[3])};
        *(ushort4*)&VTout[((size_t)((bb * 8 + hh) * 64 + dd)) * 1024 + nl] = o4;
      } else {
#pragma unroll
        for (int r = 0; r < 4; ++r) {
          const size_t off = (size_t)(row0 + r) * ldc + col;
          if (Cf) Cf[off] = v4[r];
          else Cb[off] = f2bf(v4[r]);
        }
      }
    }
  }
}

// ---------------------------------------------------------------- flash attention (MFMA)
// q64 tile, 4 waves; merged in-place SP buffer; Q pre-scaled by 0.125*log2e;
// streaming softmax (bounded scores), deferred denominator reduce.
// XCD swizzle: all 16 q-tiles of one (b,h) on one XCD (lin&127 = hb).
__global__ __launch_bounds__(256) void attn_mfma(const u16* __restrict__ QKV,
    const u16* __restrict__ Vt, const u16* __restrict__ Rb, u16* __restrict__ O) {
  const int lin = blockIdx.x;
  const int hb = lin & 127;            // (b,h) group
  const int n0 = (lin >> 7) * 64;      // q-tile
  const int h = hb & 7, b = hb >> 3;
  const int t = threadIdx.x;
  const int w = t >> 6;
  const int lc = t & 15, lq = (t >> 4) & 3;

  __shared__ __align__(16) u16 Ks[64 * 72];
  __shared__ __align__(16) u16 Vs[64 * 72];   // Vs[d][j]
  __shared__ __align__(16) u16 SP[64 * 72];   // pos scatter, then exp(S) in place

  bf16x8 qf[2];
  {
    const size_t qrow = (size_t)(b * 1024 + n0 + w * 16 + lc) * 1536 + h * 64;
    qf[0] = *(const bf16x8*)&QKV[qrow + lq * 8];
    qf[1] = *(const bf16x8*)&QKV[qrow + 32 + lq * 8];
  }

  float l_r[4] = {0.f, 0.f, 0.f, 0.f};
  f32x4 o[4];
#pragma unroll
  for (int dt = 0; dt < 4; ++dt)
#pragma unroll
    for (int r = 0; r < 4; ++r) o[dt][r] = 0.f;

  for (int jt = 0; jt < 16; ++jt) {
    const int j0 = jt * 64;
#pragma unroll
    for (int s = 0; s < 2; ++s) {
      const int f = t + 256 * s;
      const int row = f >> 3, c8 = (f & 7) * 8;
      const u16x8 kv =
          *(const u16x8*)&QKV[(size_t)(b * 1024 + j0 + row) * 1536 + 512 + h * 64 + c8];
      const u16x8 vv =
          *(const u16x8*)&Vt[(size_t)((b * 8 + h) * 64 + row) * 1024 + j0 + c8];
      *(u16x8*)&Ks[row * 72 + c8] = kv;
      *(u16x8*)&Vs[row * 72 + c8] = vv;
    }
    __syncthreads();

    f32x4 qk[4], pa[5];
#pragma unroll
    for (int j = 0; j < 4; ++j)
#pragma unroll
      for (int r = 0; r < 4; ++r) qk[j][r] = 0.f;
#pragma unroll
    for (int rtl = 0; rtl < 5; ++rtl)
#pragma unroll
      for (int r = 0; r < 4; ++r) pa[rtl][r] = 0.f;

    const int base = n0 - j0 - 63;
#pragma unroll
    for (int ks = 0; ks < 2; ++ks) {
      bf16x8 rfr[5];
#pragma unroll
      for (int rtl = 0; rtl < 5; ++rtl) {
        const int didx = (w + rtl) * 16 + lc;
        int p = base + didx;
        p = (p < -512 ? -512 : (p > 512 ? 512 : p)) + 512;
        rfr[rtl] = *(const bf16x8*)&Rb[(size_t)p * 64 + ks * 32 + lq * 8];
      }
#pragma unroll
      for (int j = 0; j < 4; ++j) {
        const bf16x8 bf = *(const bf16x8*)&Ks[(j * 16 + lc) * 72 + ks * 32 + lq * 8];
        qk[j] = __builtin_amdgcn_mfma_f32_16x16x32_bf16(qf[ks], bf, qk[j], 0, 0, 0);
      }
#pragma unroll
      for (int rtl = 0; rtl < 5; ++rtl)
        pa[rtl] = __builtin_amdgcn_mfma_f32_16x16x32_bf16(qf[ks], rfr[rtl], pa[rtl], 0, 0, 0);
    }

    // skewed scatter: P[qr][didx] -> SP[qr][jc], jc = qr - didx + 63 (wave-local)
#pragma unroll
    for (int rtl = 0; rtl < 5; ++rtl) {
      const int didx = (w + rtl) * 16 + lc;
#pragma unroll
      for (int r = 0; r < 4; ++r) {
        const int qr = w * 16 + lq * 4 + r;
        const int jc = qr - didx + 63;
        if ((unsigned)jc < 64u) SP[qr * 72 + jc] = f2bf(pa[rtl][r]);
      }
    }

    // streaming softmax in place
#pragma unroll
    for (int r = 0; r < 4; ++r) {
      const int qr = w * 16 + lq * 4 + r;
#pragma unroll
      for (int ti = 0; ti < 4; ++ti) {
        const int a = qr * 72 + ti * 16 + lc;
        const float e = exp2f(qk[ti][r] + bf2f(SP[a]));
        SP[a] = f2bf(e);
        l_r[r] += e;
      }
    }

    // PV
#pragma unroll
    for (int ks = 0; ks < 2; ++ks) {
      const bf16x8 af = *(const bf16x8*)&SP[(w * 16 + lc) * 72 + ks * 32 + lq * 8];
#pragma unroll
      for (int dt = 0; dt < 4; ++dt) {
        const bf16x8 bf = *(const bf16x8*)&Vs[(dt * 16 + lc) * 72 + ks * 32 + lq * 8];
        o[dt] = __builtin_amdgcn_mfma_f32_16x16x32_bf16(af, bf, o[dt], 0, 0, 0);
      }
    }
    __syncthreads();
  }

#pragma unroll
  for (int r = 0; r < 4; ++r) {
#pragma unroll
    for (int msk = 1; msk < 16; msk <<= 1) l_r[r] += __shfl_xor(l_r[r], msk);
  }

#pragma unroll
  for (int r = 0; r < 4; ++r) {
    const float inv = 1.f / l_r[r];
    const size_t row = (size_t)(b * 1024 + n0 + w * 16 + lq * 4 + r);
#pragma unroll
    for (int dt = 0; dt < 4; ++dt)
      O[row * 512 + h * 64 + dt * 16 + lc] = f2bf(o[dt][r] * inv);
  }
}

// ---------------------------------------------------------------- GLU (bf16)
__global__ __launch_bounds__(256) void glu_kernel(const u16* __restrict__ in,
                                                  u16* __restrict__ out) {
  const size_t m = blockIdx.x;
  const int c4 = threadIdx.x * 4;
  const ushort4 a4 = *(const ushort4*)&in[m * 2048 + c4];
  const ushort4 g4 = *(const ushort4*)&in[m * 2048 + 1024 + c4];
  ushort4 o4;
  o4.x = f2bf(bf2f(a4.x) * sigf(bf2f(g4.x)));
  o4.y = f2bf(bf2f(a4.y) * sigf(bf2f(g4.y)));
  o4.z = f2bf(bf2f(a4.z) * sigf(bf2f(g4.z)));
  o4.w = f2bf(bf2f(a4.w) * sigf(bf2f(g4.w)));
  *(ushort4*)&out[m * 1024 + c4] = o4;
}

// ---------------------------------------------------------------- depthwise conv
__global__ __launch_bounds__(256) void dwconv_kernel(const u16* __restrict__ in,
    const float* __restrict__ w, const float* __restrict__ bias,
    u16* __restrict__ out) {
  const int n0 = blockIdx.x * 64;
  const int c0 = blockIdx.y * 64;
  const int b = blockIdx.z;
  const int t = threadIdx.x;
  __shared__ float hs[94][64];
  __shared__ float wsh[31][64];
  const int c = t & 63;
  const int g = t >> 6;
  for (int r = g; r < 94; r += 4) {
    const int n = n0 - 30 + r;
    hs[r][c] = (n >= 0) ? bf2f(in[(size_t)(b * 1024 + n) * 1024 + c0 + c]) : 0.f;
  }
  for (int idx = t; idx < 31 * 64; idx += 256) {
    const int tap = idx >> 6, cc = idx & 63;
    wsh[tap][cc] = w[(size_t)(c0 + cc) * 31 + tap];
  }
  __syncthreads();
  float wr[31];
#pragma unroll
  for (int k = 0; k < 31; ++k) wr[k] = wsh[k][c];
  const float bsv = bias[c0 + c];
  float win[46];
  const int rbase = g * 16;
#pragma unroll
  for (int k = 0; k < 46; ++k) win[k] = hs[rbase + k][c];
#pragma unroll
  for (int i = 0; i < 16; ++i) {
    float acc = bsv;
#pragma unroll
    for (int k = 0; k < 31; ++k) acc += wr[k] * win[i + k];
    acc = acc * sigf(acc);
    out[(size_t)(b * 1024 + n0 + rbase + i) * 1024 + c0 + c] = f2bf(acc);
  }
}

// ---------------------------------------------------------------- launch
extern "C" void kernel_launch(void* const* d_in, const int* in_sizes, int n_in,
                              void* d_out, int out_size, void* d_ws, size_t ws_size,
                              hipStream_t stream) {
  const float* x        = (const float*)d_in[0];
  const float* ff1_ln_g = (const float*)d_in[1];
  const float* ff1_ln_b = (const float*)d_in[2];
  const float* ff1_w1   = (const float*)d_in[3];
  const float* ff1_b1   = (const float*)d_in[4];
  const float* ff1_w2   = (const float*)d_in[5];
  const float* ff1_b2   = (const float*)d_in[6];
  const float* attn_ln_g= (const float*)d_in[7];
  const float* attn_ln_b= (const float*)d_in[8];
  const float* wq       = (const float*)d_in[9];
  const float* wkv      = (const float*)d_in[10];
  const float* wo       = (const float*)d_in[11];
  const float* bo       = (const float*)d_in[12];
  const float* rel_emb  = (const float*)d_in[13];
  const float* conv_ln_g= (const float*)d_in[14];
  const float* conv_ln_b= (const float*)d_in[15];
  const float* conv1_w  = (const float*)d_in[16];
  const float* conv1_b  = (const float*)d_in[17];
  const float* dw_w     = (const float*)d_in[18];
  const float* dw_b     = (const float*)d_in[19];
  const float* conv2_w  = (const float*)d_in[20];
  const float* conv2_b  = (const float*)d_in[21];
  const float* ff2_ln_g = (const float*)d_in[22];
  const float* ff2_ln_b = (const float*)d_in[23];
  const float* ff2_w1   = (const float*)d_in[24];
  const float* ff2_b1   = (const float*)d_in[25];
  const float* ff2_w2   = (const float*)d_in[26];
  const float* ff2_b2   = (const float*)d_in[27];
  const float* post_ln_g= (const float*)d_in[28];
  const float* post_ln_b= (const float*)d_in[29];

  float* XRES = (float*)d_out;
  u16* ws = (u16*)d_ws;
  u16* LNB  = ws;                                // BN*512
  u16* HID  = LNB + (size_t)BN * 512;            // BN*2048
  u16* QKVB = HID + (size_t)BN * 2048;           // BN*1536
  u16* VT   = QKVB + (size_t)BN * 1536;          // 8192*1024
  u16* GLUB = QKVB;                              // alias (QKV dead after attn)
  u16* DWB  = HID;                               // alias (HID dead after glu)
  u16* WTp = VT + (size_t)8192 * 1024;
  u16* wt_ff1w1 = WTp;                 WTp += (size_t)2048 * 512;
  u16* wt_ff1w2 = WTp;                 WTp += (size_t)512 * 2048;
  u16* wt_qkv   = WTp;                 WTp += (size_t)1536 * 512;
  u16* wt_wo    = WTp;                 WTp += (size_t)512 * 512;
  u16* wt_conv1 = WTp;                 WTp += (size_t)2048 * 512;
  u16* wt_conv2 = WTp;                 WTp += (size_t)512 * 1024;
  u16* wt_ff2w1 = WTp;                 WTp += (size_t)2048 * 512;
  u16* wt_ff2w2 = WTp;                 WTp += (size_t)512 * 2048;
  u16* RELB     = WTp;

  const dim3 blk(256);
  const float SC = 0.125f * 1.44269504f;  // folded into Q projection

  // weight prep
  wtrans<<<dim3(64, 16), blk, 0, stream>>>(ff1_w1, wt_ff1w1, 512, 2048);
  wtrans<<<dim3(16, 64), blk, 0, stream>>>(ff1_w2, wt_ff1w2, 2048, 512);
  wtrans<<<dim3(16, 16), blk, 0, stream>>>(wq, wt_qkv, 512, 512);
  wtrans<<<dim3(32, 16), blk, 0, stream>>>(wkv, wt_qkv + (size_t)512 * 512, 512, 1024);
  wtrans<<<dim3(16, 16), blk, 0, stream>>>(wo, wt_wo, 512, 512);
  wtrans<<<dim3(64, 16), blk, 0, stream>>>(conv1_w, wt_conv1, 512, 2048);
  wtrans<<<dim3(16, 32), blk, 0, stream>>>(conv2_w, wt_conv2, 1024, 512);
  wtrans<<<dim3(64, 16), blk, 0, stream>>>(ff2_w1, wt_ff2w1, 512, 2048);
  wtrans<<<dim3(16, 64), blk, 0, stream>>>(ff2_w2, wt_ff2w2, 2048, 512);
  cvt_bf16<<<257, blk, 0, stream>>>(rel_emb, RELB, 1025 * 64);

  // --- FF1 (half-step)
  ln_kernel<<<BN, blk, 0, stream>>>(x, ff1_ln_g, ff1_ln_b, LNB, nullptr);
  gemm_bf16<<<dim3(16, 128), blk, 0, stream>>>(LNB, wt_ff1w1, ff1_b1, nullptr,
                                               nullptr, HID, nullptr, 512, 2048, 2048, 1.f, 1);
  gemm_bf16<<<dim3(4, 128), blk, 0, stream>>>(HID, wt_ff1w2, ff1_b2, x,
                                              XRES, nullptr, nullptr, 2048, 512, 512, 0.5f, 0);

  // --- attention (Q with alpha=SC; KV GEMM writes K row-major + V transposed)
  ln_kernel<<<BN, blk, 0, stream>>>(XRES, attn_ln_g, attn_ln_b, LNB, nullptr);
  gemm_bf16<<<dim3(4, 128), blk, 0, stream>>>(LNB, wt_qkv, nullptr, nullptr,
                                              nullptr, QKVB, nullptr, 512, 512, 1536, SC, 0);
  gemm_bf16<<<dim3(8, 128), blk, 0, stream>>>(LNB, wt_qkv + (size_t)512 * 512,
                                              nullptr, nullptr, nullptr, QKVB + 512,
                                              VT, 512, 1024, 1536, 1.f, 0);
  attn_mfma<<<dim3(2048), blk, 0, stream>>>(QKVB, VT, RELB, LNB);
  gemm_bf16<<<dim3(4, 128), blk, 0, stream>>>(LNB, wt_wo, bo, XRES,
                                              XRES, nullptr, nullptr, 512, 512, 512, 1.f, 0);

  // --- conv module
  ln_kernel<<<BN, blk, 0, stream>>>(XRES, conv_ln_g, conv_ln_b, LNB, nullptr);
  gemm_bf16<<<dim3(16, 128), blk, 0, stream>>>(LNB, wt_conv1, conv1_b, nullptr,
                                               nullptr, HID, nullptr, 512, 2048, 2048, 1.f, 0);
  glu_kernel<<<BN, blk, 0, stream>>>(HID, GLUB);
  dwconv_kernel<<<dim3(16, 16, 16), blk, 0, stream>>>(GLUB, dw_w, dw_b, DWB);
  gemm_bf16<<<dim3(4, 128), blk, 0, stream>>>(DWB, wt_conv2, conv2_b, XRES,
                                              XRES, nullptr, nullptr, 1024, 512, 512, 1.f, 0);

  // --- FF2 (half-step)
  ln_kernel<<<BN, blk, 0, stream>>>(XRES, ff2_ln_g, ff2_ln_b, LNB, nullptr);
  gemm_bf16<<<dim3(16, 128), blk, 0, stream>>>(LNB, wt_ff2w1, ff2_b1, nullptr,
                                               nullptr, HID, nullptr, 512, 2048, 2048, 1.f, 1);
  gemm_bf16<<<dim3(4, 128), blk, 0, stream>>>(HID, wt_ff2w2, ff2_b2, XRES,
                                              XRES, nullptr, nullptr, 2048, 512, 512, 0.5f, 0);

  // --- final layernorm
  ln_kernel<<<BN, blk, 0, stream>>>(XRES, post_ln_g, post_ln_b, nullptr, XRES);
}